// Round 1
// baseline (256.623 us; speedup 1.0000x reference)
//
#include <hip/hip_runtime.h>
#include <stdint.h>

#define SEQ 4096
#define DMODEL 768
#define NHEADS 12
#define DKH 64

typedef __attribute__((ext_vector_type(8))) short short8;
typedef __attribute__((ext_vector_type(4))) float floatx4;

__device__ __forceinline__ unsigned short f2bf(float f) {
    unsigned int u = __float_as_uint(f);
    u += 0x7fffu + ((u >> 16) & 1u);          // round-to-nearest-even
    return (unsigned short)(u >> 16);
}

// XOR swizzle for row-major bf16 tiles with 128-byte rows (64 bf16/row).
// Spreads the 16-byte slot across 8 row-distinct positions -> 2-way (free).
__device__ __forceinline__ int swz(int row, int colb) {
    return colb ^ ((row & 7) << 4);
}

// async global->LDS, 16 bytes per lane. LDS dest must be wave-uniform base;
// HW adds lane*16. Global src is per-lane.
__device__ __forceinline__ void async_copy16(void* lds, const void* g) {
    __builtin_amdgcn_global_load_lds(
        (const __attribute__((address_space(1))) void*)g,
        (__attribute__((address_space(3))) void*)lds,
        16, 0, 0);
}

// ---------------------------------------------------------------- cast f32->bf16
__global__ __launch_bounds__(256) void castk(const float* __restrict__ src,
                                             unsigned short* __restrict__ dst,
                                             int n4) {
    int i = blockIdx.x * 256 + threadIdx.x;
    if (i >= n4) return;
    float4 v = ((const float4*)src)[i];
    ushort4 o;
    o.x = f2bf(v.x); o.y = f2bf(v.y); o.z = f2bf(v.z); o.w = f2bf(v.w);
    ((ushort4*)dst)[i] = o;
}

// ---------------------------------------------------------------- GEMM  C = A * B^T
// A [4096][768] bf16 row-major, B [768][768] bf16 row-major ([out][in], i.e. B^T form).
// Tile 128x64, BK=64, 4 waves in 2x2 (each wave 64x32 output).
// MODE 0: write bf16 head-split [H][SEQ][64], value*scale.
// MODE 1: write f32 row-major [4096][768].
template <int MODE>
__global__ __launch_bounds__(256, 2)
void gemm_bt(const unsigned short* __restrict__ A,
             const unsigned short* __restrict__ B,
             void* __restrict__ Out, int K, float scale) {
    __shared__ __align__(128) char smem[(128 * 64 + 64 * 64) * 2];  // A 16KB | B 8KB
    char* As = smem;
    char* Bs = smem + 16384;

    const int t = threadIdx.x;
    const int wid = t >> 6, lane = t & 63;
    const int lr = lane & 15, lg = lane >> 4;
    const int wr = wid >> 1, wc = wid & 1;
    const int rowBase = blockIdx.x * 128;
    const int colBase = blockIdx.y * 64;

    const floatx4 zero4 = {0.f, 0.f, 0.f, 0.f};
    floatx4 acc[4][2];
#pragma unroll
    for (int m = 0; m < 4; m++)
#pragma unroll
        for (int n = 0; n < 2; n++) acc[m][n] = zero4;

    for (int kb = 0; kb < K; kb += 64) {
        __syncthreads();  // previous iteration's LDS reads done
        // stage A tile (16 KB = 4 issues of 256x16B), source pre-swizzled
#pragma unroll
        for (int i = 0; i < 4; i++) {
            int o = i * 4096 + t * 16;
            int row = o >> 7, colb = o & 127;
            const char* src = (const char*)A + ((size_t)(rowBase + row) * K + kb) * 2 + swz(row, colb);
            async_copy16(As + i * 4096 + wid * 1024, src);
        }
        // stage B tile (8 KB = 2 issues)
#pragma unroll
        for (int i = 0; i < 2; i++) {
            int o = i * 4096 + t * 16;
            int row = o >> 7, colb = o & 127;
            const char* src = (const char*)B + ((size_t)(colBase + row) * K + kb) * 2 + swz(row, colb);
            async_copy16(Bs + i * 4096 + wid * 1024, src);
        }
        __syncthreads();  // drains vmcnt -> LDS tiles ready

        short8 a[4][2], b[2][2];
#pragma unroll
        for (int m = 0; m < 4; m++)
#pragma unroll
            for (int kk = 0; kk < 2; kk++) {
                int row = wr * 64 + m * 16 + lr;
                int colb = kk * 64 + lg * 16;
                a[m][kk] = *(const short8*)(As + row * 128 + swz(row, colb));
            }
#pragma unroll
        for (int n = 0; n < 2; n++)
#pragma unroll
            for (int kk = 0; kk < 2; kk++) {
                int row = wc * 32 + n * 16 + lr;
                int colb = kk * 64 + lg * 16;
                b[n][kk] = *(const short8*)(Bs + row * 128 + swz(row, colb));
            }
#pragma unroll
        for (int m = 0; m < 4; m++)
#pragma unroll
            for (int n = 0; n < 2; n++)
#pragma unroll
                for (int kk = 0; kk < 2; kk++)
                    acc[m][n] = __builtin_amdgcn_mfma_f32_16x16x32_bf16(
                        a[m][kk], b[n][kk], acc[m][n], 0, 0, 0);
    }

    // epilogue: C/D layout col = lane&15, row = (lane>>4)*4 + reg
#pragma unroll
    for (int m = 0; m < 4; m++)
#pragma unroll
        for (int n = 0; n < 2; n++)
#pragma unroll
            for (int r = 0; r < 4; r++) {
                int srow = rowBase + wr * 64 + m * 16 + lg * 4 + r;
                int col = colBase + wc * 32 + n * 16 + lr;
                float v = acc[m][n][r] * scale;
                if (MODE == 0) {
                    int h = col >> 6, d = col & 63;
                    ((unsigned short*)Out)[((size_t)h * SEQ + srow) * DKH + d] = f2bf(v);
                } else {
                    ((float*)Out)[(size_t)srow * DMODEL + col] = v;
                }
            }
}

// ---------------------------------------------------------------- flash attention
// Q,K,V: [H][SEQ][64] bf16 (Q pre-scaled by 1/8). Output AO: [SEQ][768] bf16.
// Block: 4 waves; wave w owns q-rows [w*16, w*16+16). KVBLK=64.
__global__ __launch_bounds__(256, 2)
void attn_k(const unsigned short* __restrict__ Q,
            const unsigned short* __restrict__ Kp,
            const unsigned short* __restrict__ V,
            unsigned short* __restrict__ AO) {
    __shared__ __align__(128) char smem[8192 * 3 + 4 * 2048];  // Qs | Ks | Vt | P[4 waves]
    char* Qs = smem;
    char* Ks = smem + 8192;
    char* Vt = smem + 16384;

    const int t = threadIdx.x;
    const int wid = t >> 6, lane = t & 63;
    const int lr = lane & 15, lg = lane >> 4;
    char* Pw = smem + 24576 + wid * 2048;  // per-wave P tile [16][64] bf16 (swizzled)

    const int h = blockIdx.y, qb = blockIdx.x;
    const size_t headOff = (size_t)h * SEQ * DKH;  // elements

    // stage Q tile [64][64] once (2 issues), swizzled source
#pragma unroll
    for (int i = 0; i < 2; i++) {
        int o = i * 4096 + t * 16;
        int row = o >> 7, colb = o & 127;
        const char* src = (const char*)(Q + headOff + (size_t)(qb * 64 + row) * DKH) + swz(row, colb);
        async_copy16(Qs + i * 4096 + wid * 1024, src);
    }
    __syncthreads();

    // hoist Q fragments to registers (loop-invariant)
    short8 qf[2];
#pragma unroll
    for (int kk = 0; kk < 2; kk++) {
        int row = wid * 16 + lr;
        int colb = kk * 64 + lg * 16;
        qf[kk] = *(const short8*)(Qs + row * 128 + swz(row, colb));
    }

    const floatx4 zero4 = {0.f, 0.f, 0.f, 0.f};
    float mrun[4], lrun[4];
    floatx4 acc[4];
#pragma unroll
    for (int r = 0; r < 4; r++) { mrun[r] = -1e30f; lrun[r] = 0.f; }
#pragma unroll
    for (int f = 0; f < 4; f++) acc[f] = zero4;

    for (int kv = 0; kv < SEQ; kv += 64) {
        __syncthreads();  // all waves done reading previous K/V tiles
        // stage K tile [64][64] (2 issues), swizzled source
#pragma unroll
        for (int i = 0; i < 2; i++) {
            int o = i * 4096 + t * 16;
            int row = o >> 7, colb = o & 127;
            const char* src = (const char*)(Kp + headOff + (size_t)(kv + row) * DKH) + swz(row, colb);
            async_copy16(Ks + i * 4096 + wid * 1024, src);
        }
        // stage V transposed: Vt[f][key], swizzled. Each thread: 1 key, 16 feats.
        {
            int key = t & 63;
            int f0 = (t >> 6) * 16;
            const unsigned short* vsrc = V + headOff + (size_t)(kv + key) * DKH + f0;
            uint4 va = *(const uint4*)vsrc;
            uint4 vb = *(const uint4*)(vsrc + 8);
            const unsigned short* pa = (const unsigned short*)&va;
            const unsigned short* pb = (const unsigned short*)&vb;
#pragma unroll
            for (int j = 0; j < 8; j++) {
                int f = f0 + j;
                *(unsigned short*)(Vt + f * 128 + ((key * 2) ^ ((f & 7) << 4))) = pa[j];
            }
#pragma unroll
            for (int j = 0; j < 8; j++) {
                int f = f0 + 8 + j;
                *(unsigned short*)(Vt + f * 128 + ((key * 2) ^ ((f & 7) << 4))) = pb[j];
            }
        }
        __syncthreads();

        // QK^T: S[16 q][64 key] per wave
        floatx4 s[4];
#pragma unroll
        for (int ct = 0; ct < 4; ct++) s[ct] = zero4;
#pragma unroll
        for (int ct = 0; ct < 4; ct++)
#pragma unroll
            for (int kk = 0; kk < 2; kk++) {
                int row = ct * 16 + lr;  // key index in tile
                int colb = kk * 64 + lg * 16;
                short8 kf = *(const short8*)(Ks + row * 128 + swz(row, colb));
                s[ct] = __builtin_amdgcn_mfma_f32_16x16x32_bf16(qf[kk], kf, s[ct], 0, 0, 0);
            }

        // online softmax. Lane holds S[qrow=lg*4+r][key=ct*16+lr].
        float pv[4][4];
#pragma unroll
        for (int r = 0; r < 4; r++) {
            float mt = fmaxf(fmaxf(s[0][r], s[1][r]), fmaxf(s[2][r], s[3][r]));
#pragma unroll
            for (int off = 1; off < 16; off <<= 1) mt = fmaxf(mt, __shfl_xor(mt, off));
            float mnew = fmaxf(mrun[r], mt);
            float al = __expf(mrun[r] - mnew);
            mrun[r] = mnew;
            float sum = 0.f;
#pragma unroll
            for (int ct = 0; ct < 4; ct++) {
                float p = __expf(s[ct][r] - mnew);
                pv[ct][r] = p;
                sum += p;
            }
#pragma unroll
            for (int off = 1; off < 16; off <<= 1) sum += __shfl_xor(sum, off);
            lrun[r] = lrun[r] * al + sum;
#pragma unroll
            for (int f = 0; f < 4; f++) acc[f][r] *= al;
        }

        // write P (bf16) to per-wave LDS, swizzled
#pragma unroll
        for (int ct = 0; ct < 4; ct++)
#pragma unroll
            for (int r = 0; r < 4; r++) {
                int row = lg * 4 + r, col = ct * 16 + lr;
                *(unsigned short*)(Pw + row * 128 + ((col * 2) ^ ((row & 7) << 4))) = f2bf(pv[ct][r]);
            }
        // read P as A-fragments
        short8 pf[2];
#pragma unroll
        for (int kk = 0; kk < 2; kk++) {
            int row = lr;
            int colb = kk * 64 + lg * 16;
            pf[kk] = *(const short8*)(Pw + row * 128 + swz(row, colb));
        }
        // PV: acc[16 q][64 feat] += P * V
#pragma unroll
        for (int f = 0; f < 4; f++)
#pragma unroll
            for (int kk = 0; kk < 2; kk++) {
                int row = f * 16 + lr;  // feat index
                int colb = kk * 64 + lg * 16;
                short8 vf = *(const short8*)(Vt + row * 128 + swz(row, colb));
                acc[f] = __builtin_amdgcn_mfma_f32_16x16x32_bf16(pf[kk], vf, acc[f], 0, 0, 0);
            }
    }

    // epilogue: AO[s][h*64+f] = acc / l
#pragma unroll
    for (int f = 0; f < 4; f++)
#pragma unroll
        for (int r = 0; r < 4; r++) {
            int srow = qb * 64 + wid * 16 + lg * 4 + r;
            int col = h * DKH + f * 16 + lr;
            AO[(size_t)srow * DMODEL + col] = f2bf(acc[f][r] / lrun[r]);
        }
}

// ---------------------------------------------------------------- launch
extern "C" void kernel_launch(void* const* d_in, const int* in_sizes, int n_in,
                              void* d_out, int out_size, void* d_ws, size_t ws_size,
                              hipStream_t stream) {
    const float* x  = (const float*)d_in[0];
    const float* wq = (const float*)d_in[1];
    const float* wk = (const float*)d_in[2];
    const float* wv = (const float*)d_in[3];
    const float* wo = (const float*)d_in[4];

    char* ws = (char*)d_ws;
    unsigned short* xb  = (unsigned short*)(ws + 0);         // 4096x768 bf16
    unsigned short* wqb = (unsigned short*)(ws + 6291456);
    unsigned short* wkb = (unsigned short*)(ws + 7471104);
    unsigned short* wvb = (unsigned short*)(ws + 8650752);
    unsigned short* wob = (unsigned short*)(ws + 9830400);
    unsigned short* Qb  = (unsigned short*)(ws + 11010048);  // [12][4096][64]
    unsigned short* Kb  = (unsigned short*)(ws + 17301504);
    unsigned short* Vb  = (unsigned short*)(ws + 23592960);
    unsigned short* AOb = (unsigned short*)(ws + 29884416);  // [4096][768]

    castk<<<3072, 256, 0, stream>>>(x, xb, 786432);
    castk<<<576, 256, 0, stream>>>(wq, wqb, 147456);
    castk<<<576, 256, 0, stream>>>(wk, wkb, 147456);
    castk<<<576, 256, 0, stream>>>(wv, wvb, 147456);
    castk<<<576, 256, 0, stream>>>(wo, wob, 147456);

    dim3 g(32, 12);
    // Q pre-scaled by 1/sqrt(64) = 0.125
    gemm_bt<0><<<g, 256, 0, stream>>>(xb, wqb, Qb, DMODEL, 0.125f);
    gemm_bt<0><<<g, 256, 0, stream>>>(xb, wkb, Kb, DMODEL, 1.0f);
    gemm_bt<0><<<g, 256, 0, stream>>>(xb, wvb, Vb, DMODEL, 1.0f);

    attn_k<<<dim3(64, 12), 256, 0, stream>>>(Qb, Kb, Vb, AOb);

    gemm_bt<1><<<g, 256, 0, stream>>>(AOb, wob, d_out, DMODEL, 1.0f);
}

// Round 3
// 161.011 us; speedup vs baseline: 1.5938x; 1.5938x over previous
//
#include <hip/hip_runtime.h>
#include <stdint.h>

#define SEQ 4096
#define DMODEL 768
#define NHEADS 12
#define DKH 64

typedef __attribute__((ext_vector_type(8))) short short8;
typedef __attribute__((ext_vector_type(4))) float floatx4;

__device__ __forceinline__ unsigned short f2bf(float f) {
    unsigned int u = __float_as_uint(f);
    u += 0x7fffu + ((u >> 16) & 1u);          // round-to-nearest-even
    return (unsigned short)(u >> 16);
}

// fast 2^x — single v_exp_f32
__device__ __forceinline__ float exp2fast(float x) {
    return __builtin_amdgcn_exp2f(x);
}

// pack two f32 -> two bf16 in one instruction (lo -> bits[15:0])
__device__ __forceinline__ unsigned int cvt_pk_bf16(float lo, float hi) {
    unsigned int r;
    asm("v_cvt_pk_bf16_f32 %0, %1, %2" : "=v"(r) : "v"(lo), "v"(hi));
    return r;
}

// XOR swizzle: spread a row-strided access across 8 16-byte slots.
__device__ __forceinline__ int swz(int row, int colb) {
    return colb ^ ((row & 7) << 4);
}

// async global->LDS, 16 bytes per lane. LDS dest wave-uniform base + lane*16.
__device__ __forceinline__ void async_copy16(void* lds, const void* g) {
    __builtin_amdgcn_global_load_lds(
        (const __attribute__((address_space(1))) void*)g,
        (__attribute__((address_space(3))) void*)lds,
        16, 0, 0);
}

// ---------------------------------------------------------------- cast f32->bf16
__global__ __launch_bounds__(256) void castk(const float* __restrict__ src,
                                             unsigned short* __restrict__ dst,
                                             int n4) {
    int i = blockIdx.x * 256 + threadIdx.x;
    if (i >= n4) return;
    float4 v = ((const float4*)src)[i];
    ushort4 o;
    o.x = f2bf(v.x); o.y = f2bf(v.y); o.z = f2bf(v.z); o.w = f2bf(v.w);
    ((ushort4*)dst)[i] = o;
}

// ---------------------------------------------------------------- GEMM  C = A * B^T
// A [4096][768] bf16 row-major, B [768][768] bf16 row-major ([out][in]).
// Tile 128x64, BK=64, 4 waves 2x2.
// MODE 0: bf16 head-split [H][SEQ][64], value*scale   (Q, K)
// MODE 1: f32 row-major [4096][768]                   (final out)
// MODE 2: bf16 transposed head-split [H*64][SEQ]      (V^T)
template <int MODE>
__global__ __launch_bounds__(256, 2)
void gemm_bt(const unsigned short* __restrict__ A,
             const unsigned short* __restrict__ B,
             void* __restrict__ Out, int K, float scale) {
    __shared__ __align__(128) char smem[(128 * 64 + 64 * 64) * 2];  // A 16KB | B 8KB
    char* As = smem;
    char* Bs = smem + 16384;

    const int t = threadIdx.x;
    const int wid = t >> 6, lane = t & 63;
    const int lr = lane & 15, lg = lane >> 4;
    const int wr = wid >> 1, wc = wid & 1;
    const int rowBase = blockIdx.x * 128;
    const int colBase = blockIdx.y * 64;

    const floatx4 zero4 = {0.f, 0.f, 0.f, 0.f};
    floatx4 acc[4][2];
#pragma unroll
    for (int m = 0; m < 4; m++)
#pragma unroll
        for (int n = 0; n < 2; n++) acc[m][n] = zero4;

    for (int kb = 0; kb < K; kb += 64) {
        __syncthreads();
#pragma unroll
        for (int i = 0; i < 4; i++) {
            int o = i * 4096 + t * 16;
            int row = o >> 7, colb = o & 127;
            const char* src = (const char*)A + ((size_t)(rowBase + row) * K + kb) * 2 + swz(row, colb);
            async_copy16(As + i * 4096 + wid * 1024, src);
        }
#pragma unroll
        for (int i = 0; i < 2; i++) {
            int o = i * 4096 + t * 16;
            int row = o >> 7, colb = o & 127;
            const char* src = (const char*)B + ((size_t)(colBase + row) * K + kb) * 2 + swz(row, colb);
            async_copy16(Bs + i * 4096 + wid * 1024, src);
        }
        __syncthreads();

        short8 a[4][2], b[2][2];
#pragma unroll
        for (int m = 0; m < 4; m++)
#pragma unroll
            for (int kk = 0; kk < 2; kk++) {
                int row = wr * 64 + m * 16 + lr;
                int colb = kk * 64 + lg * 16;
                a[m][kk] = *(const short8*)(As + row * 128 + swz(row, colb));
            }
#pragma unroll
        for (int n = 0; n < 2; n++)
#pragma unroll
            for (int kk = 0; kk < 2; kk++) {
                int row = wc * 32 + n * 16 + lr;
                int colb = kk * 64 + lg * 16;
                b[n][kk] = *(const short8*)(Bs + row * 128 + swz(row, colb));
            }
#pragma unroll
        for (int m = 0; m < 4; m++)
#pragma unroll
            for (int n = 0; n < 2; n++)
#pragma unroll
                for (int kk = 0; kk < 2; kk++)
                    acc[m][n] = __builtin_amdgcn_mfma_f32_16x16x32_bf16(
                        a[m][kk], b[n][kk], acc[m][n], 0, 0, 0);
    }

#pragma unroll
    for (int m = 0; m < 4; m++)
#pragma unroll
        for (int n = 0; n < 2; n++) {
            if (MODE == 2) {
                // V^T: Out[col][srow], 4 consecutive srows per lane -> 8B store
                int srow0 = rowBase + wr * 64 + m * 16 + lg * 4;
                int col = colBase + wc * 32 + n * 16 + lr;
                ushort4 o4;
                o4.x = f2bf(acc[m][n][0] * scale);
                o4.y = f2bf(acc[m][n][1] * scale);
                o4.z = f2bf(acc[m][n][2] * scale);
                o4.w = f2bf(acc[m][n][3] * scale);
                *(ushort4*)((unsigned short*)Out + (size_t)col * SEQ + srow0) = o4;
            } else {
#pragma unroll
                for (int r = 0; r < 4; r++) {
                    int srow = rowBase + wr * 64 + m * 16 + lg * 4 + r;
                    int col = colBase + wc * 32 + n * 16 + lr;
                    float v = acc[m][n][r] * scale;
                    if (MODE == 0) {
                        int h = col >> 6, d = col & 63;
                        ((unsigned short*)Out)[((size_t)h * SEQ + srow) * DKH + d] = f2bf(v);
                    } else {
                        ((float*)Out)[(size_t)srow * DMODEL + col] = v;
                    }
                }
            }
        }
}

// ---------------------------------------------------------------- flash attention
// Q,K: [H][SEQ][64] bf16 (Q pre-scaled by log2e/8). Vt: [H*64][SEQ] bf16.
// Output AO: [SEQ][768] bf16. 4 waves; wave w owns q-rows [w*16, w*16+16).
// KVBLK=128. Swapped QK^T: S^T = mfma(K, Q), lane's q = lane&15 -> scalar m/l.
__global__ __launch_bounds__(256, 3)
void attn_k(const unsigned short* __restrict__ Q,
            const unsigned short* __restrict__ Kp,
            const unsigned short* __restrict__ Vt,
            unsigned short* __restrict__ AO) {
    // Ks [128][128B] 16K | Vs [64][256B] 16K | Qs [64][128B] 8K (reused as P
    // for waves 0,1) + 8K more P  => 48KB total, 3 blocks/CU
    __shared__ __align__(128) char smem[49152];
    char* Ks = smem;
    char* Vs = smem + 16384;
    char* Qs = smem + 32768;

    const int t = threadIdx.x;
    const int wid = t >> 6, lane = t & 63;
    const int lr = lane & 15, lg = lane >> 4;
    char* Pw = smem + 32768 + wid * 4096;  // per-wave P [16 q][256B keys]

    const int h = blockIdx.y, qb = blockIdx.x;
    const size_t headOff = (size_t)h * SEQ * DKH;

    // stage Q tile [64][64]
#pragma unroll
    for (int i = 0; i < 2; i++) {
        int o = i * 4096 + t * 16;
        int row = o >> 7, colb = o & 127;
        const char* src = (const char*)(Q + headOff + (size_t)(qb * 64 + row) * DKH) + swz(row, colb);
        async_copy16(Qs + i * 4096 + wid * 1024, src);
    }
    __syncthreads();

    short8 qf[2];
#pragma unroll
    for (int kk = 0; kk < 2; kk++) {
        int row = wid * 16 + lr;
        int colb = kk * 64 + lg * 16;
        qf[kk] = *(const short8*)(Qs + row * 128 + swz(row, colb));
    }

    const floatx4 zero4 = {0.f, 0.f, 0.f, 0.f};
    float mrun = -3.0e38f, lrun = 0.f;
    floatx4 acc[4];
#pragma unroll
    for (int f = 0; f < 4; f++) acc[f] = zero4;

    for (int kv = 0; kv < SEQ; kv += 128) {
        __syncthreads();  // all waves done reading previous K/V tiles
        // stage K tile [128][64]
#pragma unroll
        for (int i = 0; i < 4; i++) {
            int o = i * 4096 + t * 16;
            int row = o >> 7, colb = o & 127;
            const char* src = (const char*)(Kp + headOff + (size_t)(kv + row) * DKH) + swz(row, colb);
            async_copy16(Ks + i * 4096 + wid * 1024, src);
        }
        // stage V^T tile [64 feat][128 keys] straight from global V^T
#pragma unroll
        for (int i = 0; i < 4; i++) {
            int o = i * 4096 + t * 16;
            int row = o >> 8, colb = o & 255;
            const char* src = (const char*)(Vt + (size_t)(h * DKH + row) * SEQ + kv) + swz(row, colb);
            async_copy16(Vs + i * 4096 + wid * 1024, src);
        }
        __syncthreads();

        // S^T[key][q] = mfma(K, Q): col=q=lr, row(key-in-16)=lg*4+r
        floatx4 s[8];
#pragma unroll
        for (int ct = 0; ct < 8; ct++) s[ct] = zero4;
#pragma unroll
        for (int ct = 0; ct < 8; ct++)
#pragma unroll
            for (int kk = 0; kk < 2; kk++) {
                int row = ct * 16 + lr;
                int colb = kk * 64 + lg * 16;
                short8 kf = *(const short8*)(Ks + row * 128 + swz(row, colb));
                s[ct] = __builtin_amdgcn_mfma_f32_16x16x32_bf16(kf, qf[kk], s[ct], 0, 0, 0);
            }

        // online softmax: all 32 regs of this lane belong to q = lr.
        float mt = s[0][0];
#pragma unroll
        for (int ct = 0; ct < 8; ct++)
            mt = fmaxf(fmaxf(fmaxf(mt, s[ct][0]), fmaxf(s[ct][1], s[ct][2])), s[ct][3]);
        mt = fmaxf(mt, __shfl_xor(mt, 16));
        mt = fmaxf(mt, __shfl_xor(mt, 32));
        float mnew = fmaxf(mrun, mt);
        float al = exp2fast(mrun - mnew);
        float p[8][4];
        float sum = 0.f;
#pragma unroll
        for (int ct = 0; ct < 8; ct++)
#pragma unroll
            for (int r = 0; r < 4; r++) {
                float e = exp2fast(s[ct][r] - mnew);
                p[ct][r] = e;
                sum += e;
            }
        sum += __shfl_xor(sum, 16);
        sum += __shfl_xor(sum, 32);
        lrun = lrun * al + sum;
        mrun = mnew;
#pragma unroll
        for (int f = 0; f < 4; f++)
#pragma unroll
            for (int r = 0; r < 4; r++) acc[f][r] *= al;

        // write P[q=lr][key] as packed bf16 pairs (keys 16ct+4lg+2p, +2p+1)
#pragma unroll
        for (int ct = 0; ct < 8; ct++)
#pragma unroll
            for (int pp = 0; pp < 2; pp++) {
                int byteo = lr * 256 + (16 * ct + 4 * lg + 2 * pp) * 2;
                byteo ^= (lr & 7) << 4;
                *(unsigned int*)(Pw + byteo) = cvt_pk_bf16(p[ct][2 * pp], p[ct][2 * pp + 1]);
            }

        // read P fragments: lane&15 = q, k-slice = keys kk*32 + lg*8..+7
        short8 pf[4];
#pragma unroll
        for (int kk = 0; kk < 4; kk++) {
            int byteo = lr * 256 + kk * 64 + lg * 16;
            byteo ^= (lr & 7) << 4;
            pf[kk] = *(const short8*)(Pw + byteo);
        }

        // O^T[feat][q] += mfma(V^T, P)
#pragma unroll
        for (int f = 0; f < 4; f++)
#pragma unroll
            for (int kk = 0; kk < 4; kk++) {
                int row = f * 16 + lr;  // feat
                int byteo = row * 256 + kk * 64 + lg * 16;
                byteo ^= (row & 7) << 4;
                short8 vf = *(const short8*)(Vs + byteo);
                acc[f] = __builtin_amdgcn_mfma_f32_16x16x32_bf16(vf, pf[kk], acc[f], 0, 0, 0);
            }
    }

    // epilogue: acc[f][r] = O^T[feat=16f+4lg+r][q=lr]
    float inv = 1.0f / lrun;
    int srow = qb * 64 + wid * 16 + lr;
#pragma unroll
    for (int f = 0; f < 4; f++) {
        ushort4 o4;
        o4.x = f2bf(acc[f][0] * inv);
        o4.y = f2bf(acc[f][1] * inv);
        o4.z = f2bf(acc[f][2] * inv);
        o4.w = f2bf(acc[f][3] * inv);
        int col = h * DKH + f * 16 + lg * 4;
        *(ushort4*)(AO + (size_t)srow * DMODEL + col) = o4;
    }
}

// ---------------------------------------------------------------- launch
extern "C" void kernel_launch(void* const* d_in, const int* in_sizes, int n_in,
                              void* d_out, int out_size, void* d_ws, size_t ws_size,
                              hipStream_t stream) {
    const float* x  = (const float*)d_in[0];
    const float* wq = (const float*)d_in[1];
    const float* wk = (const float*)d_in[2];
    const float* wv = (const float*)d_in[3];
    const float* wo = (const float*)d_in[4];

    char* ws = (char*)d_ws;
    unsigned short* xb  = (unsigned short*)(ws + 0);         // 4096x768 bf16
    unsigned short* wqb = (unsigned short*)(ws + 6291456);
    unsigned short* wkb = (unsigned short*)(ws + 7471104);
    unsigned short* wvb = (unsigned short*)(ws + 8650752);
    unsigned short* wob = (unsigned short*)(ws + 9830400);
    unsigned short* Qb  = (unsigned short*)(ws + 11010048);  // [12][4096][64]
    unsigned short* Kb  = (unsigned short*)(ws + 17301504);  // [12][4096][64]
    unsigned short* VTb = (unsigned short*)(ws + 23592960);  // [12*64][4096]
    unsigned short* AOb = (unsigned short*)(ws + 29884416);  // [4096][768]

    castk<<<3072, 256, 0, stream>>>(x, xb, 786432);
    castk<<<576, 256, 0, stream>>>(wq, wqb, 147456);
    castk<<<576, 256, 0, stream>>>(wk, wkb, 147456);
    castk<<<576, 256, 0, stream>>>(wv, wvb, 147456);
    castk<<<576, 256, 0, stream>>>(wo, wob, 147456);

    dim3 g(32, 12);
    // Q pre-scaled by log2(e)/sqrt(64) so softmax runs in exp2 domain
    gemm_bt<0><<<g, 256, 0, stream>>>(xb, wqb, Qb, DMODEL, 0.18033688f);
    gemm_bt<0><<<g, 256, 0, stream>>>(xb, wkb, Kb, DMODEL, 1.0f);
    gemm_bt<2><<<g, 256, 0, stream>>>(xb, wvb, VTb, DMODEL, 1.0f);

    attn_k<<<dim3(64, 12), 256, 0, stream>>>(Qb, Kb, VTb, AOb);

    gemm_bt<1><<<g, 256, 0, stream>>>(AOb, wob, d_out, DMODEL, 1.0f);
}

// Round 4
// 140.511 us; speedup vs baseline: 1.8264x; 1.1459x over previous
//
#include <hip/hip_runtime.h>
#include <stdint.h>

#define SEQ 4096
#define DMODEL 768
#define NHEADS 12
#define DKH 64

typedef __attribute__((ext_vector_type(8))) short short8;
typedef __attribute__((ext_vector_type(4))) float floatx4;

__device__ __forceinline__ unsigned short f2bf(float f) {
    unsigned int u = __float_as_uint(f);
    u += 0x7fffu + ((u >> 16) & 1u);          // round-to-nearest-even
    return (unsigned short)(u >> 16);
}

// fast 2^x — single v_exp_f32
__device__ __forceinline__ float exp2fast(float x) {
    return __builtin_amdgcn_exp2f(x);
}

// pack two f32 -> two bf16 in one instruction (lo -> bits[15:0])
__device__ __forceinline__ unsigned int cvt_pk_bf16(float lo, float hi) {
    unsigned int r;
    asm("v_cvt_pk_bf16_f32 %0, %1, %2" : "=v"(r) : "v"(lo), "v"(hi));
    return r;
}

// XOR swizzle: spread a row-strided access across 8 16-byte slots.
__device__ __forceinline__ int swz(int row, int colb) {
    return colb ^ ((row & 7) << 4);
}

// async global->LDS, 16 bytes per lane. LDS dest wave-uniform base + lane*16.
__device__ __forceinline__ void async_copy16(void* lds, const void* g) {
    __builtin_amdgcn_global_load_lds(
        (const __attribute__((address_space(1))) void*)g,
        (__attribute__((address_space(3))) void*)lds,
        16, 0, 0);
}

// ---------------------------------------------------------------- cast f32->bf16
__global__ __launch_bounds__(256) void castk(const float* __restrict__ src,
                                             unsigned short* __restrict__ dst,
                                             int n4) {
    int i = blockIdx.x * 256 + threadIdx.x;
    if (i >= n4) return;
    float4 v = ((const float4*)src)[i];
    ushort4 o;
    o.x = f2bf(v.x); o.y = f2bf(v.y); o.z = f2bf(v.z); o.w = f2bf(v.w);
    ((ushort4*)dst)[i] = o;
}

// ---------------------------------------------------------------- GEMM  C = A * B^T
// A [4096][768] bf16 row-major, B [768][768] bf16 row-major ([out][in]).
// Tile 128x64, BK=64, 4 waves 2x2.
// MODE 0: bf16 head-split [H][SEQ][64], value*scale   (Q, K)
// MODE 1: f32 row-major [4096][768]                   (final out)
// MODE 2: bf16 transposed head-split [H*64][SEQ], columns permuted within each
//         32-key block by pos(z) = 8*((z>>2)&3) + 4*((z>>4)&1) + (z&3)  (V^T)
template <int MODE>
__global__ __launch_bounds__(256, 2)
void gemm_bt(const unsigned short* __restrict__ A,
             const unsigned short* __restrict__ B,
             void* __restrict__ Out, int K, float scale) {
    __shared__ __align__(128) char smem[(128 * 64 + 64 * 64) * 2];  // A 16KB | B 8KB
    char* As = smem;
    char* Bs = smem + 16384;

    const int t = threadIdx.x;
    const int wid = t >> 6, lane = t & 63;
    const int lr = lane & 15, lg = lane >> 4;
    const int wr = wid >> 1, wc = wid & 1;
    const int rowBase = blockIdx.x * 128;
    const int colBase = blockIdx.y * 64;

    const floatx4 zero4 = {0.f, 0.f, 0.f, 0.f};
    floatx4 acc[4][2];
#pragma unroll
    for (int m = 0; m < 4; m++)
#pragma unroll
        for (int n = 0; n < 2; n++) acc[m][n] = zero4;

    for (int kb = 0; kb < K; kb += 64) {
        __syncthreads();
#pragma unroll
        for (int i = 0; i < 4; i++) {
            int o = i * 4096 + t * 16;
            int row = o >> 7, colb = o & 127;
            const char* src = (const char*)A + ((size_t)(rowBase + row) * K + kb) * 2 + swz(row, colb);
            async_copy16(As + i * 4096 + wid * 1024, src);
        }
#pragma unroll
        for (int i = 0; i < 2; i++) {
            int o = i * 4096 + t * 16;
            int row = o >> 7, colb = o & 127;
            const char* src = (const char*)B + ((size_t)(colBase + row) * K + kb) * 2 + swz(row, colb);
            async_copy16(Bs + i * 4096 + wid * 1024, src);
        }
        __syncthreads();

        short8 a[4][2], b[2][2];
#pragma unroll
        for (int m = 0; m < 4; m++)
#pragma unroll
            for (int kk = 0; kk < 2; kk++) {
                int row = wr * 64 + m * 16 + lr;
                int colb = kk * 64 + lg * 16;
                a[m][kk] = *(const short8*)(As + row * 128 + swz(row, colb));
            }
#pragma unroll
        for (int n = 0; n < 2; n++)
#pragma unroll
            for (int kk = 0; kk < 2; kk++) {
                int row = wc * 32 + n * 16 + lr;
                int colb = kk * 64 + lg * 16;
                b[n][kk] = *(const short8*)(Bs + row * 128 + swz(row, colb));
            }
#pragma unroll
        for (int m = 0; m < 4; m++)
#pragma unroll
            for (int n = 0; n < 2; n++)
#pragma unroll
                for (int kk = 0; kk < 2; kk++)
                    acc[m][n] = __builtin_amdgcn_mfma_f32_16x16x32_bf16(
                        a[m][kk], b[n][kk], acc[m][n], 0, 0, 0);
    }

#pragma unroll
    for (int m = 0; m < 4; m++)
#pragma unroll
        for (int n = 0; n < 2; n++) {
            if (MODE == 2) {
                // V^T: Out[col][pos(srow)], 4 consecutive keys -> 8B store
                int srow0 = rowBase + wr * 64 + m * 16 + lg * 4;
                int z = srow0 & 31;
                int pos0 = (srow0 & ~31) + 8 * ((z >> 2) & 3) + 4 * (z >> 4);
                int col = colBase + wc * 32 + n * 16 + lr;
                ushort4 o4;
                o4.x = f2bf(acc[m][n][0] * scale);
                o4.y = f2bf(acc[m][n][1] * scale);
                o4.z = f2bf(acc[m][n][2] * scale);
                o4.w = f2bf(acc[m][n][3] * scale);
                *(ushort4*)((unsigned short*)Out + (size_t)col * SEQ + pos0) = o4;
            } else {
#pragma unroll
                for (int r = 0; r < 4; r++) {
                    int srow = rowBase + wr * 64 + m * 16 + lg * 4 + r;
                    int col = colBase + wc * 32 + n * 16 + lr;
                    float v = acc[m][n][r] * scale;
                    if (MODE == 0) {
                        int h = col >> 6, d = col & 63;
                        ((unsigned short*)Out)[((size_t)h * SEQ + srow) * DKH + d] = f2bf(v);
                    } else {
                        ((float*)Out)[(size_t)srow * DMODEL + col] = v;
                    }
                }
            }
        }
}

// ---------------------------------------------------------------- flash attention
// Q,K: [H][SEQ][64] bf16 (Q pre-scaled by log2e/8). Vt: [H*64][SEQ] bf16,
// column-permuted per 32-block (see gemm_bt MODE 2). Output AO: [SEQ][768] bf16.
// 4 waves; wave w owns q-rows [w*16, w*16+16). KVBLK=128.
// Swapped QK^T: S^T = mfma(K, Q), lane's q = lane&15 -> scalar m/l.
// P never touches LDS: key-permutation makes the PV B-fragment lane-local.
__global__ __launch_bounds__(256, 4)
void attn_k(const unsigned short* __restrict__ Q,
            const unsigned short* __restrict__ Kp,
            const unsigned short* __restrict__ Vt,
            unsigned short* __restrict__ AO) {
    // Ks [128 keys][128B] 16K | Vs [64 feat][256B] 16K  => 32KB, 4+ blocks/CU
    __shared__ __align__(128) char smem[32768];
    char* Ks = smem;
    char* Vs = smem + 16384;

    const int t = threadIdx.x;
    const int wid = t >> 6, lane = t & 63;
    const int lr = lane & 15, lg = lane >> 4;

    const int h = blockIdx.y, qb = blockIdx.x;
    const size_t headOff = (size_t)h * SEQ * DKH;

    // Q fragments via direct global loads (done once, no LDS)
    const unsigned short* qptr = Q + headOff + (size_t)(qb * 64 + wid * 16 + lr) * DKH + lg * 8;
    short8 qf[2];
    qf[0] = *(const short8*)qptr;
    qf[1] = *(const short8*)(qptr + 32);

    const short8 ones8 = {(short)0x3F80, (short)0x3F80, (short)0x3F80, (short)0x3F80,
                          (short)0x3F80, (short)0x3F80, (short)0x3F80, (short)0x3F80};
    const floatx4 zero4 = {0.f, 0.f, 0.f, 0.f};
    float mrun = -3.0e38f;
    floatx4 acc[4];
    floatx4 acc_l = zero4;
#pragma unroll
    for (int f = 0; f < 4; f++) acc[f] = zero4;

    for (int kv = 0; kv < SEQ; kv += 128) {
        __syncthreads();  // all waves done reading previous K/V tiles
        // stage K tile [128][64]
#pragma unroll
        for (int i = 0; i < 4; i++) {
            int o = i * 4096 + t * 16;
            int row = o >> 7, colb = o & 127;
            const char* src = (const char*)(Kp + headOff + (size_t)(kv + row) * DKH) + swz(row, colb);
            async_copy16(Ks + i * 4096 + wid * 1024, src);
        }
        // stage V^T tile [64 feat][128 keys] (global already column-permuted)
#pragma unroll
        for (int i = 0; i < 4; i++) {
            int o = i * 4096 + t * 16;
            int row = o >> 8, colb = o & 255;
            const char* src = (const char*)(Vt + (size_t)(h * DKH + row) * SEQ + kv) + swz(row, colb);
            async_copy16(Vs + i * 4096 + wid * 1024, src);
        }
        __syncthreads();

        // S^T[key][q] = mfma(K, Q): lane holds keys 16ct+4lg+r, q = lr
        floatx4 s[8];
#pragma unroll
        for (int ct = 0; ct < 8; ct++) s[ct] = zero4;
#pragma unroll
        for (int ct = 0; ct < 8; ct++)
#pragma unroll
            for (int kk = 0; kk < 2; kk++) {
                int row = ct * 16 + lr;
                int colb = kk * 64 + lg * 16;
                short8 kf = *(const short8*)(Ks + row * 128 + swz(row, colb));
                s[ct] = __builtin_amdgcn_mfma_f32_16x16x32_bf16(kf, qf[kk], s[ct], 0, 0, 0);
            }

        // online softmax (exp2 domain); row max across 4 lane-groups
        float mt = s[0][0];
#pragma unroll
        for (int ct = 0; ct < 8; ct++)
            mt = fmaxf(fmaxf(fmaxf(mt, s[ct][0]), fmaxf(s[ct][1], s[ct][2])), s[ct][3]);
        mt = fmaxf(mt, __shfl_xor(mt, 16));
        mt = fmaxf(mt, __shfl_xor(mt, 32));
        // defer-max: skip rescale while max grows < 2^8
        if (!__all(mt <= mrun + 8.0f)) {
            float mnew = fmaxf(mrun, mt);
            float al = exp2fast(mrun - mnew);
#pragma unroll
            for (int f = 0; f < 4; f++)
#pragma unroll
                for (int r = 0; r < 4; r++) acc[f][r] *= al;
            acc_l[0] *= al;
            mrun = mnew;
        }
        // P = exp2(S - mrun), in place
#pragma unroll
        for (int ct = 0; ct < 8; ct++)
#pragma unroll
            for (int r = 0; r < 4; r++) s[ct][r] = exp2fast(s[ct][r] - mrun);

        // PV + row-sum. Key-permuted fragments: pf[kk] is lane-local.
#pragma unroll
        for (int kk = 0; kk < 4; kk++) {
            uint4 pw;
            pw.x = cvt_pk_bf16(s[2 * kk][0], s[2 * kk][1]);
            pw.y = cvt_pk_bf16(s[2 * kk][2], s[2 * kk][3]);
            pw.z = cvt_pk_bf16(s[2 * kk + 1][0], s[2 * kk + 1][1]);
            pw.w = cvt_pk_bf16(s[2 * kk + 1][2], s[2 * kk + 1][3]);
            short8 pf = *(const short8*)&pw;
#pragma unroll
            for (int f = 0; f < 4; f++) {
                int row = f * 16 + lr;  // feat
                int byteo = row * 256 + kk * 64 + lg * 16;
                byteo ^= (row & 7) << 4;
                short8 vf = *(const short8*)(Vs + byteo);
                acc[f] = __builtin_amdgcn_mfma_f32_16x16x32_bf16(vf, pf, acc[f], 0, 0, 0);
            }
            acc_l = __builtin_amdgcn_mfma_f32_16x16x32_bf16(ones8, pf, acc_l, 0, 0, 0);
        }
    }

    // epilogue: acc[f][r] = O^T[feat=16f+4lg+r][q=lr]; l = acc_l[0]
    float inv = 1.0f / acc_l[0];
    int srow = qb * 64 + wid * 16 + lr;
#pragma unroll
    for (int f = 0; f < 4; f++) {
        ushort4 o4;
        o4.x = f2bf(acc[f][0] * inv);
        o4.y = f2bf(acc[f][1] * inv);
        o4.z = f2bf(acc[f][2] * inv);
        o4.w = f2bf(acc[f][3] * inv);
        int col = h * DKH + f * 16 + lg * 4;
        *(ushort4*)(AO + (size_t)srow * DMODEL + col) = o4;
    }
}

// ---------------------------------------------------------------- launch
extern "C" void kernel_launch(void* const* d_in, const int* in_sizes, int n_in,
                              void* d_out, int out_size, void* d_ws, size_t ws_size,
                              hipStream_t stream) {
    const float* x  = (const float*)d_in[0];
    const float* wq = (const float*)d_in[1];
    const float* wk = (const float*)d_in[2];
    const float* wv = (const float*)d_in[3];
    const float* wo = (const float*)d_in[4];

    char* ws = (char*)d_ws;
    unsigned short* xb  = (unsigned short*)(ws + 0);         // 4096x768 bf16
    unsigned short* wqb = (unsigned short*)(ws + 6291456);
    unsigned short* wkb = (unsigned short*)(ws + 7471104);
    unsigned short* wvb = (unsigned short*)(ws + 8650752);
    unsigned short* wob = (unsigned short*)(ws + 9830400);
    unsigned short* Qb  = (unsigned short*)(ws + 11010048);  // [12][4096][64]
    unsigned short* Kb  = (unsigned short*)(ws + 17301504);  // [12][4096][64]
    unsigned short* VTb = (unsigned short*)(ws + 23592960);  // [12*64][4096] permuted
    unsigned short* AOb = (unsigned short*)(ws + 29884416);  // [4096][768]

    castk<<<3072, 256, 0, stream>>>(x, xb, 786432);
    castk<<<576, 256, 0, stream>>>(wq, wqb, 147456);
    castk<<<576, 256, 0, stream>>>(wk, wkb, 147456);
    castk<<<576, 256, 0, stream>>>(wv, wvb, 147456);
    castk<<<576, 256, 0, stream>>>(wo, wob, 147456);

    dim3 g(32, 12);
    // Q pre-scaled by log2(e)/sqrt(64) so softmax runs in exp2 domain
    gemm_bt<0><<<g, 256, 0, stream>>>(xb, wqb, Qb, DMODEL, 0.18033688f);
    gemm_bt<0><<<g, 256, 0, stream>>>(xb, wkb, Kb, DMODEL, 1.0f);
    gemm_bt<2><<<g, 256, 0, stream>>>(xb, wvb, VTb, DMODEL, 1.0f);

    attn_k<<<dim3(64, 12), 256, 0, stream>>>(Qb, Kb, VTb, AOb);

    gemm_bt<1><<<g, 256, 0, stream>>>(AOb, wob, d_out, DMODEL, 1.0f);
}

// Round 5
// 132.796 us; speedup vs baseline: 1.9325x; 1.0581x over previous
//
#include <hip/hip_runtime.h>
#include <stdint.h>

#define SEQ 4096
#define DMODEL 768
#define NHEADS 12
#define DKH 64

typedef __attribute__((ext_vector_type(8))) short short8;
typedef __attribute__((ext_vector_type(4))) float floatx4;

__device__ __forceinline__ unsigned short f2bf(float f) {
    unsigned int u = __float_as_uint(f);
    u += 0x7fffu + ((u >> 16) & 1u);          // round-to-nearest-even
    return (unsigned short)(u >> 16);
}

__device__ __forceinline__ float exp2fast(float x) {
    return __builtin_amdgcn_exp2f(x);
}

__device__ __forceinline__ unsigned int cvt_pk_bf16(float lo, float hi) {
    unsigned int r;
    asm("v_cvt_pk_bf16_f32 %0, %1, %2" : "=v"(r) : "v"(lo), "v"(hi));
    return r;
}

// XOR swizzle: spread a row-strided access across 8 16-byte slots.
__device__ __forceinline__ int swz(int row, int colb) {
    return colb ^ ((row & 7) << 4);
}

// async global->LDS, 16 bytes per lane. LDS dest wave-uniform base + lane*16.
__device__ __forceinline__ void async_copy16(void* lds, const void* g) {
    __builtin_amdgcn_global_load_lds(
        (const __attribute__((address_space(1))) void*)g,
        (__attribute__((address_space(3))) void*)lds,
        16, 0, 0);
}

// ---------------------------------------------------------------- casts
__global__ __launch_bounds__(256) void castk(const float* __restrict__ src,
                                             unsigned short* __restrict__ dst,
                                             int n4) {
    int i = blockIdx.x * 256 + threadIdx.x;
    if (i >= n4) return;
    float4 v = ((const float4*)src)[i];
    ushort4 o;
    o.x = f2bf(v.x); o.y = f2bf(v.y); o.z = f2bf(v.z); o.w = f2bf(v.w);
    ((ushort4*)dst)[i] = o;
}

// all four 768x768 weights in one launch; dst regions contiguous
__global__ __launch_bounds__(256) void castw(const float* __restrict__ w0,
                                             const float* __restrict__ w1,
                                             const float* __restrict__ w2,
                                             const float* __restrict__ w3,
                                             unsigned short* __restrict__ dst) {
    int b = blockIdx.x;              // 2304 = 4 * 576
    int wsel = b / 576;
    int i = (b % 576) * 256 + threadIdx.x;   // < 147456 float4 groups
    const float* src = (wsel == 0) ? w0 : (wsel == 1) ? w1 : (wsel == 2) ? w2 : w3;
    float4 v = ((const float4*)src)[i];
    ushort4 o;
    o.x = f2bf(v.x); o.y = f2bf(v.y); o.z = f2bf(v.z); o.w = f2bf(v.w);
    ((ushort4*)(dst + (size_t)wsel * 589824))[i] = o;
}

// stage one 128x64 A-tile + 64x64 B-tile into LDS buffer (6 loads/wave)
#define STAGE_G(bsel, kb)                                                              \
    do {                                                                               \
        char* As_ = smem + (bsel) * 24576;                                             \
        _Pragma("unroll") for (int ii = 0; ii < 4; ii++) {                             \
            int o = ii * 4096 + t * 16;                                                \
            int row = o >> 7, colb = o & 127;                                          \
            async_copy16(As_ + ii * 4096 + wid * 1024,                                 \
                         (const char*)A + ((size_t)(rowBase + row) * DMODEL + (kb)) * 2 \
                             + swz(row, colb));                                        \
        }                                                                              \
        _Pragma("unroll") for (int ii = 0; ii < 2; ii++) {                             \
            int o = ii * 4096 + t * 16;                                                \
            int row = o >> 7, colb = o & 127;                                          \
            async_copy16(As_ + 16384 + ii * 4096 + wid * 1024,                         \
                         (const char*)B + ((size_t)(colBase + row) * DMODEL + (kb)) * 2 \
                             + swz(row, colb));                                        \
        }                                                                              \
    } while (0)

// shared inner compute for the 128x64 GEMM tile (16 MFMA per wave)
#define GEMM_COMPUTE(As, Bs)                                                           \
    do {                                                                               \
        short8 a_[4][2], b_[2][2];                                                     \
        _Pragma("unroll") for (int m = 0; m < 4; m++)                                  \
            _Pragma("unroll") for (int kk = 0; kk < 2; kk++) {                         \
                int row = wr * 64 + m * 16 + lr;                                       \
                int colb = kk * 64 + lg * 16;                                          \
                a_[m][kk] = *(const short8*)((As) + row * 128 + swz(row, colb));       \
            }                                                                          \
        _Pragma("unroll") for (int n = 0; n < 2; n++)                                  \
            _Pragma("unroll") for (int kk = 0; kk < 2; kk++) {                         \
                int row = wc * 32 + n * 16 + lr;                                       \
                int colb = kk * 64 + lg * 16;                                          \
                b_[n][kk] = *(const short8*)((Bs) + row * 128 + swz(row, colb));       \
            }                                                                          \
        _Pragma("unroll") for (int m = 0; m < 4; m++)                                  \
            _Pragma("unroll") for (int n = 0; n < 2; n++)                              \
                _Pragma("unroll") for (int kk = 0; kk < 2; kk++)                       \
                    acc[m][n] = __builtin_amdgcn_mfma_f32_16x16x32_bf16(               \
                        a_[m][kk], b_[n][kk], acc[m][n], 0, 0, 0);                     \
    } while (0)

// ---------------------------------------------------------------- fused QKV GEMM
// A [4096][768] bf16; W = wq|wk|wv contiguous ([out][in] each).
// grid (32, 36): by/12 = proj (0:Q scaled, 1:K, 2:V^T), by%12 = col tile.
// Out: Qb | Kb ([H][SEQ][64]) | VTb ([768][SEQ], 32-key-block permuted).
__global__ __launch_bounds__(256, 2)
void gemm_qkv(const unsigned short* __restrict__ A,
              const unsigned short* __restrict__ W,
              unsigned short* __restrict__ OutBase, float qscale) {
    __shared__ __align__(128) char smem[49152];  // 2 x (A 16K | B 8K)

    const int t = threadIdx.x;
    const int wid = t >> 6, lane = t & 63;
    const int lr = lane & 15, lg = lane >> 4;
    const int wr = wid >> 1, wc = wid & 1;
    const int rowBase = blockIdx.x * 128;
    const int proj = blockIdx.y / 12;
    const int colBase = (blockIdx.y % 12) * 64;
    const unsigned short* B = W + (size_t)proj * 589824;

    const floatx4 zero4 = {0.f, 0.f, 0.f, 0.f};
    floatx4 acc[4][2];
#pragma unroll
    for (int m = 0; m < 4; m++)
#pragma unroll
        for (int n = 0; n < 2; n++) acc[m][n] = zero4;

    STAGE_G(0, 0);
    for (int i = 0; i < 12; ++i) {
        __builtin_amdgcn_s_barrier();              // all waves done reading buf[(i+1)&1]
        __builtin_amdgcn_sched_barrier(0);
        if (i < 11) {
            STAGE_G((i + 1) & 1, (i + 1) * 64);
            asm volatile("s_waitcnt vmcnt(6)" ::: "memory");  // own stage(i) done
        } else {
            asm volatile("s_waitcnt vmcnt(0)" ::: "memory");
        }
        __builtin_amdgcn_s_barrier();              // everyone's stage(i) done
        __builtin_amdgcn_sched_barrier(0);
        char* As = smem + (i & 1) * 24576;
        GEMM_COMPUTE(As, As + 16384);
    }

    if (proj < 2) {
        unsigned short* O = OutBase + (size_t)proj * 3145728;
        float scale = (proj == 0) ? qscale : 1.0f;
#pragma unroll
        for (int m = 0; m < 4; m++)
#pragma unroll
            for (int n = 0; n < 2; n++)
#pragma unroll
                for (int r = 0; r < 4; r++) {
                    int srow = rowBase + wr * 64 + m * 16 + lg * 4 + r;
                    int col = colBase + wc * 32 + n * 16 + lr;
                    int h = col >> 6, d = col & 63;
                    O[((size_t)h * SEQ + srow) * DKH + d] = f2bf(acc[m][n][r] * scale);
                }
    } else {
        unsigned short* O = OutBase + 6291456;  // V^T [768][SEQ]
#pragma unroll
        for (int m = 0; m < 4; m++)
#pragma unroll
            for (int n = 0; n < 2; n++) {
                int srow0 = rowBase + wr * 64 + m * 16 + lg * 4;
                int z = srow0 & 31;
                int pos0 = (srow0 & ~31) + 8 * ((z >> 2) & 3) + 4 * (z >> 4);
                int col = colBase + wc * 32 + n * 16 + lr;
                ushort4 o4;
                o4.x = f2bf(acc[m][n][0]);
                o4.y = f2bf(acc[m][n][1]);
                o4.z = f2bf(acc[m][n][2]);
                o4.w = f2bf(acc[m][n][3]);
                *(ushort4*)(O + (size_t)col * SEQ + pos0) = o4;
            }
    }
}

// ---------------------------------------------------------------- output GEMM
// A = AO [4096][768] bf16, B = wo [768][768] bf16, out f32 [4096][768].
__global__ __launch_bounds__(256, 2)
void gemm_o(const unsigned short* __restrict__ A,
            const unsigned short* __restrict__ B,
            float* __restrict__ Out) {
    __shared__ __align__(128) char smem[49152];

    const int t = threadIdx.x;
    const int wid = t >> 6, lane = t & 63;
    const int lr = lane & 15, lg = lane >> 4;
    const int wr = wid >> 1, wc = wid & 1;
    const int rowBase = blockIdx.x * 128;
    const int colBase = blockIdx.y * 64;

    const floatx4 zero4 = {0.f, 0.f, 0.f, 0.f};
    floatx4 acc[4][2];
#pragma unroll
    for (int m = 0; m < 4; m++)
#pragma unroll
        for (int n = 0; n < 2; n++) acc[m][n] = zero4;

    STAGE_G(0, 0);
    for (int i = 0; i < 12; ++i) {
        __builtin_amdgcn_s_barrier();
        __builtin_amdgcn_sched_barrier(0);
        if (i < 11) {
            STAGE_G((i + 1) & 1, (i + 1) * 64);
            asm volatile("s_waitcnt vmcnt(6)" ::: "memory");
        } else {
            asm volatile("s_waitcnt vmcnt(0)" ::: "memory");
        }
        __builtin_amdgcn_s_barrier();
        __builtin_amdgcn_sched_barrier(0);
        char* As = smem + (i & 1) * 24576;
        GEMM_COMPUTE(As, As + 16384);
    }

#pragma unroll
    for (int m = 0; m < 4; m++)
#pragma unroll
        for (int n = 0; n < 2; n++)
#pragma unroll
            for (int r = 0; r < 4; r++) {
                int srow = rowBase + wr * 64 + m * 16 + lg * 4 + r;
                int col = colBase + wc * 32 + n * 16 + lr;
                Out[(size_t)srow * DMODEL + col] = acc[m][n][r];
            }
}

// ---------------------------------------------------------------- flash attention
// Q,K: [H][SEQ][64] bf16 (Q pre-scaled by log2e/8). Vt: [768][SEQ] bf16,
// column-permuted per 32-key block. AO: [SEQ][768] bf16.
// KVBLK=64, 3 LDS buffers, single raw barrier + counted vmcnt per tile.
// Swapped QK^T; P stays in registers (key-permutation matches V^T layout).
#define STAGE_A(bsel, kv0)                                                             \
    do {                                                                               \
        char* Kd_ = smem + (bsel) * 16384;                                             \
        _Pragma("unroll") for (int ii = 0; ii < 2; ii++) {                             \
            int o = ii * 4096 + t * 16;                                                \
            int row = o >> 7, colb = o & 127;                                          \
            async_copy16(Kd_ + ii * 4096 + wid * 1024,                                 \
                         (const char*)(Kp + headOff + (size_t)((kv0) + row) * DKH)     \
                             + swz(row, colb));                                        \
        }                                                                              \
        _Pragma("unroll") for (int ii = 0; ii < 2; ii++) {                             \
            int o = ii * 4096 + t * 16;                                                \
            int row = o >> 7, colb = o & 127;                                          \
            async_copy16(Kd_ + 8192 + ii * 4096 + wid * 1024,                          \
                         (const char*)(Vt + (size_t)(h * DKH + row) * SEQ + (kv0))     \
                             + swz(row, colb));                                        \
        }                                                                              \
    } while (0)

__global__ __launch_bounds__(256, 4)
void attn_k(const unsigned short* __restrict__ Q,
            const unsigned short* __restrict__ Kp,
            const unsigned short* __restrict__ Vt,
            unsigned short* __restrict__ AO) {
    __shared__ __align__(128) char smem[49152];  // 3 x (Ks 8K | Vs 8K)

    const int t = threadIdx.x;
    const int wid = t >> 6, lane = t & 63;
    const int lr = lane & 15, lg = lane >> 4;

    // XCD-aware bijective swizzle: 768 blocks = 8 XCDs x 96 -> each XCD sees <=2 heads
    int nid = (blockIdx.x & 7) * 96 + (blockIdx.x >> 3);
    const int h = nid >> 6, qb = nid & 63;
    const size_t headOff = (size_t)h * SEQ * DKH;

    // Q fragments via direct global loads
    const unsigned short* qptr = Q + headOff + (size_t)(qb * 64 + wid * 16 + lr) * DKH + lg * 8;
    short8 qf[2];
    qf[0] = *(const short8*)qptr;
    qf[1] = *(const short8*)(qptr + 32);

    const short8 ones8 = {(short)0x3F80, (short)0x3F80, (short)0x3F80, (short)0x3F80,
                          (short)0x3F80, (short)0x3F80, (short)0x3F80, (short)0x3F80};
    const floatx4 zero4 = {0.f, 0.f, 0.f, 0.f};
    float mrun = -3.0e38f;
    floatx4 acc[4];
    floatx4 acc_l = zero4;
#pragma unroll
    for (int f = 0; f < 4; f++) acc[f] = zero4;

    STAGE_A(0, 0);
    STAGE_A(1, 64);

    int cA = 0;  // buffer holding tile tt
    for (int tt = 0; tt < 64; ++tt) {
        if (tt < 62) asm volatile("s_waitcnt vmcnt(4)" ::: "memory");  // tile tt landed
        else         asm volatile("s_waitcnt vmcnt(0)" ::: "memory");
        __builtin_amdgcn_s_barrier();            // all waves' tile tt complete,
        __builtin_amdgcn_sched_barrier(0);       // all done computing tile tt-1
        if (tt < 62) {
            int cC = cA + 2; if (cC >= 3) cC -= 3;
            STAGE_A(cC, (tt + 2) * 64);
        }
        char* Ks = smem + cA * 16384;
        char* Vs = Ks + 8192;

        // S^T[key][q] = mfma(K, Q): lane holds keys 16ct+4lg+r, q = lr
        floatx4 s[4];
#pragma unroll
        for (int ct = 0; ct < 4; ct++) s[ct] = zero4;
#pragma unroll
        for (int ct = 0; ct < 4; ct++)
#pragma unroll
            for (int kk = 0; kk < 2; kk++) {
                int row = ct * 16 + lr;
                int colb = kk * 64 + lg * 16;
                short8 kf = *(const short8*)(Ks + row * 128 + swz(row, colb));
                s[ct] = __builtin_amdgcn_mfma_f32_16x16x32_bf16(kf, qf[kk], s[ct], 0, 0, 0);
            }

        // online softmax (exp2 domain)
        float mt = s[0][0];
#pragma unroll
        for (int ct = 0; ct < 4; ct++)
            mt = fmaxf(fmaxf(fmaxf(mt, s[ct][0]), fmaxf(s[ct][1], s[ct][2])), s[ct][3]);
        mt = fmaxf(mt, __shfl_xor(mt, 16));
        mt = fmaxf(mt, __shfl_xor(mt, 32));
        if (!__all(mt <= mrun + 8.0f)) {        // defer-max (T13)
            float mnew = fmaxf(mrun, mt);
            float al = exp2fast(mrun - mnew);
#pragma unroll
            for (int f = 0; f < 4; f++)
#pragma unroll
                for (int r = 0; r < 4; r++) acc[f][r] *= al;
            acc_l[0] *= al;
            mrun = mnew;
        }
#pragma unroll
        for (int ct = 0; ct < 4; ct++)
#pragma unroll
            for (int r = 0; r < 4; r++) s[ct][r] = exp2fast(s[ct][r] - mrun);

        // PV + row-sum; key-permuted fragments are lane-local
#pragma unroll
        for (int kk = 0; kk < 2; kk++) {
            uint4 pw;
            pw.x = cvt_pk_bf16(s[2 * kk][0], s[2 * kk][1]);
            pw.y = cvt_pk_bf16(s[2 * kk][2], s[2 * kk][3]);
            pw.z = cvt_pk_bf16(s[2 * kk + 1][0], s[2 * kk + 1][1]);
            pw.w = cvt_pk_bf16(s[2 * kk + 1][2], s[2 * kk + 1][3]);
            short8 pf = *(const short8*)&pw;
#pragma unroll
            for (int f = 0; f < 4; f++) {
                int row = f * 16 + lr;
                int byteo = (row * 128 + kk * 64 + lg * 16) ^ ((row & 7) << 4);
                short8 vf = *(const short8*)(Vs + byteo);
                acc[f] = __builtin_amdgcn_mfma_f32_16x16x32_bf16(vf, pf, acc[f], 0, 0, 0);
            }
            acc_l = __builtin_amdgcn_mfma_f32_16x16x32_bf16(ones8, pf, acc_l, 0, 0, 0);
        }

        cA = (cA == 2) ? 0 : cA + 1;
    }

    // epilogue: acc[f][r] = O^T[feat=16f+4lg+r][q=lr]; l = acc_l[0]
    float inv = 1.0f / acc_l[0];
    int srow = qb * 64 + wid * 16 + lr;
#pragma unroll
    for (int f = 0; f < 4; f++) {
        ushort4 o4;
        o4.x = f2bf(acc[f][0] * inv);
        o4.y = f2bf(acc[f][1] * inv);
        o4.z = f2bf(acc[f][2] * inv);
        o4.w = f2bf(acc[f][3] * inv);
        int col = h * DKH + f * 16 + lg * 4;
        *(ushort4*)(AO + (size_t)srow * DMODEL + col) = o4;
    }
}

// ---------------------------------------------------------------- launch
extern "C" void kernel_launch(void* const* d_in, const int* in_sizes, int n_in,
                              void* d_out, int out_size, void* d_ws, size_t ws_size,
                              hipStream_t stream) {
    const float* x  = (const float*)d_in[0];
    const float* wq = (const float*)d_in[1];
    const float* wk = (const float*)d_in[2];
    const float* wv = (const float*)d_in[3];
    const float* wo = (const float*)d_in[4];

    char* ws = (char*)d_ws;
    unsigned short* xb  = (unsigned short*)(ws + 0);         // 4096x768 bf16
    unsigned short* wqb = (unsigned short*)(ws + 6291456);   // wq|wk|wv|wo contiguous
    unsigned short* wob = (unsigned short*)(ws + 9830400);
    unsigned short* Qb  = (unsigned short*)(ws + 11010048);  // Q|K|V^T contiguous
    unsigned short* Kb  = (unsigned short*)(ws + 17301504);
    unsigned short* VTb = (unsigned short*)(ws + 23592960);  // [768][4096] permuted
    unsigned short* AOb = (unsigned short*)(ws + 29884416);  // [4096][768]

    castk<<<3072, 256, 0, stream>>>(x, xb, 786432);
    castw<<<2304, 256, 0, stream>>>(wq, wk, wv, wo, wqb);

    // Q pre-scaled by log2(e)/sqrt(64) so softmax runs in exp2 domain
    gemm_qkv<<<dim3(32, 36), 256, 0, stream>>>(xb, wqb, Qb, 0.18033688f);

    attn_k<<<dim3(768), 256, 0, stream>>>(Qb, Kb, VTb, AOb);

    gemm_o<<<dim3(32, 12), 256, 0, stream>>>(AOb, wob, (float*)d_out);
}

// Round 6
// 118.459 us; speedup vs baseline: 2.1663x; 1.1210x over previous
//
#include <hip/hip_runtime.h>
#include <stdint.h>

#define SEQ 4096
#define DMODEL 768
#define NHEADS 12
#define DKH 64

typedef __attribute__((ext_vector_type(8))) short short8;
typedef __attribute__((ext_vector_type(4))) float floatx4;

__device__ __forceinline__ unsigned short f2bf(float f) {
    unsigned int u = __float_as_uint(f);
    u += 0x7fffu + ((u >> 16) & 1u);          // round-to-nearest-even
    return (unsigned short)(u >> 16);
}

__device__ __forceinline__ float exp2fast(float x) {
    return __builtin_amdgcn_exp2f(x);
}

__device__ __forceinline__ unsigned int cvt_pk_bf16(float lo, float hi) {
    unsigned int r;
    asm("v_cvt_pk_bf16_f32 %0, %1, %2" : "=v"(r) : "v"(lo), "v"(hi));
    return r;
}

// XOR swizzle: spread a row-strided access across 8 16-byte slots.
__device__ __forceinline__ int swz(int row, int colb) {
    return colb ^ ((row & 7) << 4);
}

// async global->LDS, 16 bytes per lane. LDS dest wave-uniform base + lane*16.
__device__ __forceinline__ void async_copy16(void* lds, const void* g) {
    __builtin_amdgcn_global_load_lds(
        (const __attribute__((address_space(1))) void*)g,
        (__attribute__((address_space(3))) void*)lds,
        16, 0, 0);
}

// ---------------------------------------------------------------- casts
__global__ __launch_bounds__(256) void castk(const float* __restrict__ src,
                                             unsigned short* __restrict__ dst,
                                             int n4) {
    int i = blockIdx.x * 256 + threadIdx.x;
    if (i >= n4) return;
    float4 v = ((const float4*)src)[i];
    ushort4 o;
    o.x = f2bf(v.x); o.y = f2bf(v.y); o.z = f2bf(v.z); o.w = f2bf(v.w);
    ((ushort4*)dst)[i] = o;
}

// all four 768x768 weights in one launch; dst regions contiguous
__global__ __launch_bounds__(256) void castw(const float* __restrict__ w0,
                                             const float* __restrict__ w1,
                                             const float* __restrict__ w2,
                                             const float* __restrict__ w3,
                                             unsigned short* __restrict__ dst) {
    int b = blockIdx.x;              // 2304 = 4 * 576
    int wsel = b / 576;
    int i = (b % 576) * 256 + threadIdx.x;   // < 147456 float4 groups
    const float* src = (wsel == 0) ? w0 : (wsel == 1) ? w1 : (wsel == 2) ? w2 : w3;
    float4 v = ((const float4*)src)[i];
    ushort4 o;
    o.x = f2bf(v.x); o.y = f2bf(v.y); o.z = f2bf(v.z); o.w = f2bf(v.w);
    ((ushort4*)(dst + (size_t)wsel * 589824))[i] = o;
}

// stage one 128x64 A-tile + 64x64 B-tile into LDS buffer (6 loads/wave)
#define STAGE_G(bsel, kb)                                                              \
    do {                                                                               \
        char* As_ = smem + (bsel) * 24576;                                             \
        _Pragma("unroll") for (int ii = 0; ii < 4; ii++) {                             \
            int o = ii * 4096 + t * 16;                                                \
            int row = o >> 7, colb = o & 127;                                          \
            async_copy16(As_ + ii * 4096 + wid * 1024,                                 \
                         (const char*)A + ((size_t)(rowBase + row) * DMODEL + (kb)) * 2 \
                             + swz(row, colb));                                        \
        }                                                                              \
        _Pragma("unroll") for (int ii = 0; ii < 2; ii++) {                             \
            int o = ii * 4096 + t * 16;                                                \
            int row = o >> 7, colb = o & 127;                                          \
            async_copy16(As_ + 16384 + ii * 4096 + wid * 1024,                         \
                         (const char*)B + ((size_t)(colBase + row) * DMODEL + (kb)) * 2 \
                             + swz(row, colb));                                        \
        }                                                                              \
    } while (0)

// shared inner compute for the 128x64 GEMM tile (16 MFMA per wave)
#define GEMM_COMPUTE(As, Bs)                                                           \
    do {                                                                               \
        short8 a_[4][2], b_[2][2];                                                     \
        _Pragma("unroll") for (int m = 0; m < 4; m++)                                  \
            _Pragma("unroll") for (int kk = 0; kk < 2; kk++) {                         \
                int row = wr * 64 + m * 16 + lr;                                       \
                int colb = kk * 64 + lg * 16;                                          \
                a_[m][kk] = *(const short8*)((As) + row * 128 + swz(row, colb));       \
            }                                                                          \
        _Pragma("unroll") for (int n = 0; n < 2; n++)                                  \
            _Pragma("unroll") for (int kk = 0; kk < 2; kk++) {                         \
                int row = wc * 32 + n * 16 + lr;                                       \
                int colb = kk * 64 + lg * 16;                                          \
                b_[n][kk] = *(const short8*)((Bs) + row * 128 + swz(row, colb));       \
            }                                                                          \
        _Pragma("unroll") for (int m = 0; m < 4; m++)                                  \
            _Pragma("unroll") for (int n = 0; n < 2; n++)                              \
                _Pragma("unroll") for (int kk = 0; kk < 2; kk++)                       \
                    acc[m][n] = __builtin_amdgcn_mfma_f32_16x16x32_bf16(               \
                        a_[m][kk], b_[n][kk], acc[m][n], 0, 0, 0);                     \
    } while (0)

// ---------------------------------------------------------------- fused QKV GEMM
// A [4096][768] bf16; W = wq|wk|wv contiguous ([out][in] each).
// grid (32, 36): by/12 = proj (0:Q scaled, 1:K, 2:V^T), by%12 = col tile.
// Out: Qb | Kb ([H][SEQ][64]) | VTb ([768][SEQ], 32-key-block permuted).
__global__ __launch_bounds__(256, 2)
void gemm_qkv(const unsigned short* __restrict__ A,
              const unsigned short* __restrict__ W,
              unsigned short* __restrict__ OutBase, float qscale) {
    __shared__ __align__(128) char smem[49152];  // 2 x (A 16K | B 8K)

    const int t = threadIdx.x;
    const int wid = t >> 6, lane = t & 63;
    const int lr = lane & 15, lg = lane >> 4;
    const int wr = wid >> 1, wc = wid & 1;
    const int rowBase = blockIdx.x * 128;
    const int proj = blockIdx.y / 12;
    const int colBase = (blockIdx.y % 12) * 64;
    const unsigned short* B = W + (size_t)proj * 589824;

    const floatx4 zero4 = {0.f, 0.f, 0.f, 0.f};
    floatx4 acc[4][2];
#pragma unroll
    for (int m = 0; m < 4; m++)
#pragma unroll
        for (int n = 0; n < 2; n++) acc[m][n] = zero4;

    STAGE_G(0, 0);
    for (int i = 0; i < 12; ++i) {
        __builtin_amdgcn_s_barrier();              // all waves done reading buf[(i+1)&1]
        __builtin_amdgcn_sched_barrier(0);
        if (i < 11) {
            STAGE_G((i + 1) & 1, (i + 1) * 64);
            asm volatile("s_waitcnt vmcnt(6)" ::: "memory");  // own stage(i) done
        } else {
            asm volatile("s_waitcnt vmcnt(0)" ::: "memory");
        }
        __builtin_amdgcn_s_barrier();              // everyone's stage(i) done
        __builtin_amdgcn_sched_barrier(0);
        char* As = smem + (i & 1) * 24576;
        GEMM_COMPUTE(As, As + 16384);
    }

    if (proj < 2) {
        unsigned short* O = OutBase + (size_t)proj * 3145728;
        float scale = (proj == 0) ? qscale : 1.0f;
#pragma unroll
        for (int m = 0; m < 4; m++)
#pragma unroll
            for (int n = 0; n < 2; n++)
#pragma unroll
                for (int r = 0; r < 4; r++) {
                    int srow = rowBase + wr * 64 + m * 16 + lg * 4 + r;
                    int col = colBase + wc * 32 + n * 16 + lr;
                    int h = col >> 6, d = col & 63;
                    O[((size_t)h * SEQ + srow) * DKH + d] = f2bf(acc[m][n][r] * scale);
                }
    } else {
        unsigned short* O = OutBase + 6291456;  // V^T [768][SEQ]
#pragma unroll
        for (int m = 0; m < 4; m++)
#pragma unroll
            for (int n = 0; n < 2; n++) {
                int srow0 = rowBase + wr * 64 + m * 16 + lg * 4;
                int z = srow0 & 31;
                int pos0 = (srow0 & ~31) + 8 * ((z >> 2) & 3) + 4 * (z >> 4);
                int col = colBase + wc * 32 + n * 16 + lr;
                ushort4 o4;
                o4.x = f2bf(acc[m][n][0]);
                o4.y = f2bf(acc[m][n][1]);
                o4.z = f2bf(acc[m][n][2]);
                o4.w = f2bf(acc[m][n][3]);
                *(ushort4*)(O + (size_t)col * SEQ + pos0) = o4;
            }
    }
}

// ---------------------------------------------------------------- output GEMM
// A = AO [4096][768] bf16, B = wo [768][768] bf16, out f32 [4096][768].
__global__ __launch_bounds__(256, 2)
void gemm_o(const unsigned short* __restrict__ A,
            const unsigned short* __restrict__ B,
            float* __restrict__ Out) {
    __shared__ __align__(128) char smem[49152];

    const int t = threadIdx.x;
    const int wid = t >> 6, lane = t & 63;
    const int lr = lane & 15, lg = lane >> 4;
    const int wr = wid >> 1, wc = wid & 1;
    const int rowBase = blockIdx.x * 128;
    const int colBase = blockIdx.y * 64;

    const floatx4 zero4 = {0.f, 0.f, 0.f, 0.f};
    floatx4 acc[4][2];
#pragma unroll
    for (int m = 0; m < 4; m++)
#pragma unroll
        for (int n = 0; n < 2; n++) acc[m][n] = zero4;

    STAGE_G(0, 0);
    for (int i = 0; i < 12; ++i) {
        __builtin_amdgcn_s_barrier();
        __builtin_amdgcn_sched_barrier(0);
        if (i < 11) {
            STAGE_G((i + 1) & 1, (i + 1) * 64);
            asm volatile("s_waitcnt vmcnt(6)" ::: "memory");
        } else {
            asm volatile("s_waitcnt vmcnt(0)" ::: "memory");
        }
        __builtin_amdgcn_s_barrier();
        __builtin_amdgcn_sched_barrier(0);
        char* As = smem + (i & 1) * 24576;
        GEMM_COMPUTE(As, As + 16384);
    }

#pragma unroll
    for (int m = 0; m < 4; m++)
#pragma unroll
        for (int n = 0; n < 2; n++)
#pragma unroll
            for (int r = 0; r < 4; r++) {
                int srow = rowBase + wr * 64 + m * 16 + lg * 4 + r;
                int col = colBase + wc * 32 + n * 16 + lr;
                Out[(size_t)srow * DMODEL + col] = acc[m][n][r];
            }
}

// ---------------------------------------------------------------- flash attention
// Q,K: [H][SEQ][64] bf16 (Q pre-scaled by log2e/8). Vt: [768][SEQ] bf16,
// column-permuted per 32-key block. AO: [SEQ][768] bf16.
// KVBLK=128. LDS: K double-buffer (2x16K) + V single buffer (16K) = 48KB
// -> 3 blocks/CU, exact fit for the 768-block grid.
// Per tile: vmcnt(0)+barrier (K(t) visible everywhere, V buffer free) ->
// issue V(t) then K(t+1) -> QK^T+softmax (covers V latency) ->
// vmcnt(4)+barrier (V(t) visible, K(t+1) stays in flight) -> PV.
#define STAGE_KA(bsel, kv0)                                                            \
    do {                                                                               \
        char* Kd_ = smem + (bsel) * 16384;                                             \
        _Pragma("unroll") for (int ii = 0; ii < 4; ii++) {                             \
            int o = ii * 4096 + t * 16;                                                \
            int row = o >> 7, colb = o & 127;                                          \
            async_copy16(Kd_ + ii * 4096 + wid * 1024,                                 \
                         (const char*)(Kp + headOff + (size_t)((kv0) + row) * DKH)     \
                             + swz(row, colb));                                        \
        }                                                                              \
    } while (0)

#define STAGE_VA(kv0)                                                                  \
    do {                                                                               \
        char* Vd_ = smem + 32768;                                                      \
        _Pragma("unroll") for (int ii = 0; ii < 4; ii++) {                             \
            int o = ii * 4096 + t * 16;                                                \
            int row = o >> 8, colb = o & 255;                                          \
            async_copy16(Vd_ + ii * 4096 + wid * 1024,                                 \
                         (const char*)(Vt + (size_t)(h * DKH + row) * SEQ + (kv0))     \
                             + swz(row, colb));                                        \
        }                                                                              \
    } while (0)

__global__ __launch_bounds__(256, 3)
void attn_k(const unsigned short* __restrict__ Q,
            const unsigned short* __restrict__ Kp,
            const unsigned short* __restrict__ Vt,
            unsigned short* __restrict__ AO) {
    __shared__ __align__(128) char smem[49152];  // K0 16K | K1 16K | V 16K

    const int t = threadIdx.x;
    const int wid = t >> 6, lane = t & 63;
    const int lr = lane & 15, lg = lane >> 4;

    // XCD-aware bijective swizzle: 768 blocks = 8 XCDs x 96 -> each XCD sees <=2 heads
    int nid = (blockIdx.x & 7) * 96 + (blockIdx.x >> 3);
    const int h = nid >> 6, qb = nid & 63;
    const size_t headOff = (size_t)h * SEQ * DKH;

    // Q fragments via direct global loads
    const unsigned short* qptr = Q + headOff + (size_t)(qb * 64 + wid * 16 + lr) * DKH + lg * 8;
    short8 qf[2];
    qf[0] = *(const short8*)qptr;
    qf[1] = *(const short8*)(qptr + 32);

    const short8 ones8 = {(short)0x3F80, (short)0x3F80, (short)0x3F80, (short)0x3F80,
                          (short)0x3F80, (short)0x3F80, (short)0x3F80, (short)0x3F80};
    const floatx4 zero4 = {0.f, 0.f, 0.f, 0.f};
    float mrun = -3.0e38f;
    floatx4 acc[4];
    floatx4 acc_l = zero4;
#pragma unroll
    for (int f = 0; f < 4; f++) acc[f] = zero4;

    STAGE_KA(0, 0);

    for (int tt = 0; tt < 32; ++tt) {
        asm volatile("s_waitcnt vmcnt(0)" ::: "memory");  // own K(tt) retired (full-tile cover)
        __builtin_amdgcn_s_barrier();        // all waves: K(tt) visible; PV(tt-1) done -> V free
        __builtin_amdgcn_sched_barrier(0);
        STAGE_VA(tt * 128);                  // V(tt): covered by QK^T + softmax
        if (tt < 31) STAGE_KA((tt + 1) & 1, (tt + 1) * 128);  // K(tt+1): full-tile cover
        __builtin_amdgcn_sched_barrier(0);

        char* Ks = smem + (tt & 1) * 16384;
        char* Vs = smem + 32768;

        // S^T[key][q] = mfma(K, Q): lane holds keys 16ct+4lg+r, q = lr
        floatx4 s[8];
#pragma unroll
        for (int ct = 0; ct < 8; ct++) s[ct] = zero4;
        __builtin_amdgcn_s_setprio(1);
#pragma unroll
        for (int ct = 0; ct < 8; ct++)
#pragma unroll
            for (int kk = 0; kk < 2; kk++) {
                int row = ct * 16 + lr;
                int colb = kk * 64 + lg * 16;
                short8 kf = *(const short8*)(Ks + row * 128 + swz(row, colb));
                s[ct] = __builtin_amdgcn_mfma_f32_16x16x32_bf16(kf, qf[kk], s[ct], 0, 0, 0);
            }
        __builtin_amdgcn_s_setprio(0);

        // online softmax (exp2 domain); balanced max tree
        float cm[8];
#pragma unroll
        for (int ct = 0; ct < 8; ct++)
            cm[ct] = fmaxf(fmaxf(s[ct][0], s[ct][1]), fmaxf(s[ct][2], s[ct][3]));
        float mt = fmaxf(fmaxf(fmaxf(cm[0], cm[1]), fmaxf(cm[2], cm[3])),
                         fmaxf(fmaxf(cm[4], cm[5]), fmaxf(cm[6], cm[7])));
        mt = fmaxf(mt, __shfl_xor(mt, 16));
        mt = fmaxf(mt, __shfl_xor(mt, 32));
        if (!__all(mt <= mrun + 8.0f)) {        // defer-max (T13)
            float mnew = fmaxf(mrun, mt);
            float al = exp2fast(mrun - mnew);
#pragma unroll
            for (int f = 0; f < 4; f++)
#pragma unroll
                for (int r = 0; r < 4; r++) acc[f][r] *= al;
            acc_l[0] *= al;
            mrun = mnew;
        }
#pragma unroll
        for (int ct = 0; ct < 8; ct++)
#pragma unroll
            for (int r = 0; r < 4; r++) s[ct][r] = exp2fast(s[ct][r] - mrun);

        if (tt < 31) asm volatile("s_waitcnt vmcnt(4)" ::: "memory");  // V(tt) retired, K in flight
        else         asm volatile("s_waitcnt vmcnt(0)" ::: "memory");
        __builtin_amdgcn_s_barrier();        // all waves' V(tt) visible
        __builtin_amdgcn_sched_barrier(0);

        // PV + row-sum; key-permuted fragments are lane-local
        __builtin_amdgcn_s_setprio(1);
#pragma unroll
        for (int kk = 0; kk < 4; kk++) {
            uint4 pw;
            pw.x = cvt_pk_bf16(s[2 * kk][0], s[2 * kk][1]);
            pw.y = cvt_pk_bf16(s[2 * kk][2], s[2 * kk][3]);
            pw.z = cvt_pk_bf16(s[2 * kk + 1][0], s[2 * kk + 1][1]);
            pw.w = cvt_pk_bf16(s[2 * kk + 1][2], s[2 * kk + 1][3]);
            short8 pf = *(const short8*)&pw;
#pragma unroll
            for (int f = 0; f < 4; f++) {
                int row = f * 16 + lr;
                int byteo = (row * 256 + kk * 64 + lg * 16) ^ ((row & 7) << 4);
                short8 vf = *(const short8*)(Vs + byteo);
                acc[f] = __builtin_amdgcn_mfma_f32_16x16x32_bf16(vf, pf, acc[f], 0, 0, 0);
            }
            acc_l = __builtin_amdgcn_mfma_f32_16x16x32_bf16(ones8, pf, acc_l, 0, 0, 0);
        }
        __builtin_amdgcn_s_setprio(0);
    }

    // epilogue: acc[f][r] = O^T[feat=16f+4lg+r][q=lr]; l = acc_l[0]
    float inv = 1.0f / acc_l[0];
    int srow = qb * 64 + wid * 16 + lr;
#pragma unroll
    for (int f = 0; f < 4; f++) {
        ushort4 o4;
        o4.x = f2bf(acc[f][0] * inv);
        o4.y = f2bf(acc[f][1] * inv);
        o4.z = f2bf(acc[f][2] * inv);
        o4.w = f2bf(acc[f][3] * inv);
        int col = h * DKH + f * 16 + lg * 4;
        *(ushort4*)(AO + (size_t)srow * DMODEL + col) = o4;
    }
}

// ---------------------------------------------------------------- launch
extern "C" void kernel_launch(void* const* d_in, const int* in_sizes, int n_in,
                              void* d_out, int out_size, void* d_ws, size_t ws_size,
                              hipStream_t stream) {
    const float* x  = (const float*)d_in[0];
    const float* wq = (const float*)d_in[1];
    const float* wk = (const float*)d_in[2];
    const float* wv = (const float*)d_in[3];
    const float* wo = (const float*)d_in[4];

    char* ws = (char*)d_ws;
    unsigned short* xb  = (unsigned short*)(ws + 0);         // 4096x768 bf16
    unsigned short* wqb = (unsigned short*)(ws + 6291456);   // wq|wk|wv|wo contiguous
    unsigned short* wob = (unsigned short*)(ws + 9830400);
    unsigned short* Qb  = (unsigned short*)(ws + 11010048);  // Q|K|V^T contiguous
    unsigned short* Kb  = (unsigned short*)(ws + 17301504);
    unsigned short* VTb = (unsigned short*)(ws + 23592960);  // [768][4096] permuted
    unsigned short* AOb = (unsigned short*)(ws + 29884416);  // [4096][768]

    castk<<<3072, 256, 0, stream>>>(x, xb, 786432);
    castw<<<2304, 256, 0, stream>>>(wq, wk, wv, wo, wqb);

    // Q pre-scaled by log2(e)/sqrt(64) so softmax runs in exp2 domain
    gemm_qkv<<<dim3(32, 36), 256, 0, stream>>>(xb, wqb, Qb, 0.18033688f);

    attn_k<<<dim3(768), 256, 0, stream>>>(Qb, Kb, VTb, AOb);

    gemm_o<<<dim3(32, 12), 256, 0, stream>>>(AOb, wob, (float*)d_out);
}